// Round 15
// baseline (17.334 us; speedup 1.0000x reference)
//
#include <hip/hip_runtime.h>
#include <math.h>

#define N_BOX 8192
#define NT 1024
#define TOPK_CAP 128
#define IOU_THR 0.3f
#define M_TARGET 116u
#define CAP_C 128
#define BINA_SHIFT 22        // 10-bit coarse bin
#define BINB_SHIFT 12        // bits [12,22) refine (1024 bins)
#define SENT 0xFFFFFFFFu

typedef unsigned long long u64;

// scan 1024-bin histogram for cumulative crossing of `target`
__device__ __forceinline__ void wave_scan_1024(const unsigned* hist,
                                               unsigned* outw,
                                               unsigned target, int lane)
{
    uint4 h0 = ((const uint4*)hist)[lane * 4 + 0];
    uint4 h1 = ((const uint4*)hist)[lane * 4 + 1];
    uint4 h2 = ((const uint4*)hist)[lane * 4 + 2];
    uint4 h3 = ((const uint4*)hist)[lane * 4 + 3];
    unsigned b[16] = {h0.x, h0.y, h0.z, h0.w, h1.x, h1.y, h1.z, h1.w,
                      h2.x, h2.y, h2.z, h2.w, h3.x, h3.y, h3.z, h3.w};
    unsigned s = 0;
#pragma unroll
    for (int k = 0; k < 16; k++) s += b[k];
    unsigned incl = s;
    for (int off = 1; off < 64; off <<= 1) {
        unsigned n = __shfl_up(incl, off);
        if (lane >= off) incl += n;
    }
    unsigned excl = incl - s;
    if (excl < target && excl + s >= target) {
        unsigned run = excl;
        bool found = false;
#pragma unroll
        for (int k = 0; k < 16; k++) {
            unsigned nrun = run + b[k];
            if (!found && nrun >= target) {
                outw[0] = (unsigned)(lane * 16 + k);
                outw[1] = nrun;
                outw[2] = run;
                found = true;
            }
            run = nrun;
        }
    }
}

// ------ single fused kernel ------
__global__ __launch_bounds__(NT)
void pd_post_kernel(const float* __restrict__ x,
                    const float* __restrict__ y,
                    const float* __restrict__ anchors,
                    float* __restrict__ out,
                    int top_k)
{
#pragma clang fp contract(off)
    __shared__ unsigned s_histA[1024];                 // fallback only
    __shared__ unsigned s_histB[1024];
    __shared__ unsigned s_wred[16];
    __shared__ unsigned s_scan[8];                     // [0..2] B-scan, [3]=G, [4..6] A-scan
    __shared__ u64 s_cand[CAP_C];
    __shared__ u64 s_sorted[CAP_C];
    __shared__ float4 s_boxtmp[CAP_C];                 // boxes in compact order
    __shared__ float4 s_sbox[CAP_C];                   // boxes in sorted order
    __shared__ unsigned short s_mrow[CAP_C][8];
    __shared__ u64 s_rnz[2];
    __shared__ short s_keeppos[TOPK_CAP];
    __shared__ int s_cnt, s_nkept;

    const int tid = threadIdx.x;
    const int lane = tid & 63;
    const int wv = tid >> 6;
    const float inv128 = 0.0078125f;

    // ---- issue x loads first (32 KB coalesced) ----
    const uint4* xp = (const uint4*)x;
    uint4 xa = xp[tid * 2 + 0];
    uint4 xb = xp[tid * 2 + 1];

    // ---- init LDS while loads are in flight ----
    if (tid == 0) s_cnt = 0;
    if (tid < 2) s_rnz[tid] = 0ull;
    if (tid < 8) s_scan[tid] = SENT;
    if (tid < 256) {
        uint4 z = make_uint4(0u, 0u, 0u, 0u);
        ((uint4*)s_histB)[tid] = z;
    }
    if (tid < CAP_C) {
        s_cand[tid] = ~0ull;
        s_sorted[tid] = ~0ull;
        s_sbox[tid] = make_float4(3e30f, 3e30f, 3e30f, 3e30f);   // sentinel default
    }

    // ---- keys = ~(bits(sigmoid(x))|sign), in registers ----
    unsigned xs[8] = {xa.x, xa.y, xa.z, xa.w, xb.x, xb.y, xb.z, xb.w};
    unsigned myk[8];
    unsigned mymin = 0xFFFFFFFFu;
#pragma unroll
    for (int k = 0; k < 8; k++) {
        float xv = __uint_as_float(xs[k]);
        float s = 1.0f / (1.0f + expf(-xv));
        unsigned kk = ~(__float_as_uint(s) | 0x80000000u);
        myk[k] = kk;
        mymin = (kk < mymin) ? kk : mymin;
    }

    // ---- block min -> first nonempty coarse bin G ----
#pragma unroll
    for (int off = 32; off >= 1; off >>= 1) {
        unsigned o = (unsigned)__shfl_xor((int)mymin, off);
        mymin = (o < mymin) ? o : mymin;
    }
    if (lane == 0) s_wred[wv] = mymin;
    __syncthreads();                                          // B1
    if (wv == 0) {
        unsigned v = (lane < 16) ? s_wred[lane] : 0xFFFFFFFFu;
#pragma unroll
        for (int off = 8; off >= 1; off >>= 1) {
            unsigned o = (unsigned)__shfl_xor((int)v, off);
            v = (o < v) ? o : v;
        }
        if (lane == 0) s_scan[3] = v >> BINA_SHIFT;
    }
    __syncthreads();                                          // B2
    const unsigned G = s_scan[3];

    // ---- fast pass-B histogram (bin-G keys on bits [12,22)) ----
#pragma unroll
    for (int k = 0; k < 8; k++)
        if ((myk[k] >> BINA_SHIFT) == G)
            atomicAdd(&s_histB[(myk[k] >> BINB_SHIFT) & 1023u], 1u);
    __syncthreads();                                          // B3
    if (wv == 0) wave_scan_1024(s_histB, &s_scan[0], M_TARGET, lane);
    __syncthreads();                                          // B4

    unsigned B1bin, B2sub;
    int C;
    if (s_scan[0] != SENT) {
        B1bin = G;
        B2sub = s_scan[0];
        C = (int)s_scan[1];
    } else {
        // ---- fallback (block-uniform; proven two-level path) ----
        if (tid < 256) {
            uint4 z = make_uint4(0u, 0u, 0u, 0u);
            ((uint4*)s_histA)[tid] = z;
        }
        __syncthreads();
#pragma unroll
        for (int k = 0; k < 8; k++)
            atomicAdd(&s_histA[myk[k] >> BINA_SHIFT], 1u);
        __syncthreads();
        if (wv == 0) wave_scan_1024(s_histA, &s_scan[4], M_TARGET, lane);
        __syncthreads();
        B1bin = s_scan[4];
        unsigned n0 = s_scan[6];
        if (tid < 256) {
            uint4 z = make_uint4(0u, 0u, 0u, 0u);
            ((uint4*)s_histB)[tid] = z;
        }
        __syncthreads();
#pragma unroll
        for (int k = 0; k < 8; k++)
            if ((myk[k] >> BINA_SHIFT) == B1bin)
                atomicAdd(&s_histB[(myk[k] >> BINB_SHIFT) & 1023u], 1u);
        __syncthreads();
        if (wv == 0) wave_scan_1024(s_histB, &s_scan[0], M_TARGET - n0, lane);
        __syncthreads();
        B2sub = s_scan[0];
        C = (int)(n0 + s_scan[1]);
    }
    if (C > CAP_C) C = CAP_C;

    // ---- compact (ballot-aggregated) + inline box decode ----
#pragma unroll
    for (int k = 0; k < 8; k++) {
        unsigned kk = myk[k];
        unsigned b1 = kk >> BINA_SHIFT;
        bool sel = (b1 < B1bin) || (b1 == B1bin && ((kk >> BINB_SHIFT) & 1023u) <= B2sub);
        u64 mask = __ballot(sel);
        if (mask) {
            int base = 0;
            if (lane == 0) base = atomicAdd(&s_cnt, __builtin_popcountll(mask));
            base = __shfl(base, 0);
            if (sel) {
                int p = base + __builtin_popcountll(mask & ((1ull << lane) - 1ull));
                if (p < CAP_C) {
                    int idx = tid * 8 + k;
                    s_cand[p] = (((u64)kk) << 32) | (unsigned)idx;
                    const float2* yr = (const float2*)(y + idx * 18);
                    float2 ya = yr[0];
                    float2 yb2 = yr[1];
                    float2 an = ((const float2*)anchors)[idx];
                    float cx = ya.x * inv128 + an.x;
                    float cy = ya.y * inv128 + an.y;
                    float w2 = (yb2.x * inv128) * 0.5f;
                    float h2 = (yb2.y * inv128) * 0.5f;
                    s_boxtmp[p] = make_float4(cx - w2, cy - h2, cx + w2, cy + h2);
                }
            }
        }
    }
    __syncthreads();                                          // B5

    // ---- rank sort; scatter keys AND boxes by rank ----
    if (tid < CAP_C) {
        u64 me = s_cand[tid];
        int rank = 0;
        const ulonglong2* cp = (const ulonglong2*)s_cand;
#pragma unroll
        for (int j = 0; j < CAP_C / 2; j += 4) {
            ulonglong2 a = cp[j + 0];
            ulonglong2 b = cp[j + 1];
            ulonglong2 d = cp[j + 2];
            ulonglong2 e = cp[j + 3];
            rank += (a.x < me) + (a.y < me) + (b.x < me) + (b.y < me)
                  + (d.x < me) + (d.y < me) + (e.x < me) + (e.y < me);
        }
        if (me != ~0ull) {
            s_sorted[rank] = me;
            s_sbox[rank] = s_boxtmp[tid];
        }
    }
    __syncthreads();                                          // B6

    // ---- build upper-tri suppression matrix: (row, 16-col group) per thread ----
    {
        int row = tid >> 3;
        int g = tid & 7;
        int c0 = g << 4;
        unsigned bits = 0u;
        if (c0 + 15 > row) {
            float4 A = s_sbox[row];
            float aA = (A.z - A.x) * (A.w - A.y);
#pragma unroll
            for (int k = 0; k < 16; ++k) {
                int kk = (k + row) & 15;
                float4 Bx = s_sbox[c0 + kk];
                float ba = (Bx.z - Bx.x) * (Bx.w - Bx.y);
                float iw = fmaxf(fminf(A.z, Bx.z) - fmaxf(A.x, Bx.x), 0.0f);
                float ih = fmaxf(fminf(A.w, Bx.w) - fmaxf(A.y, Bx.y), 0.0f);
                float inter = iw * ih;
                float iou = inter / (aA + ba - inter);
                if (iou > IOU_THR) bits |= (1u << kk);
            }
            if (row >= c0) {
                int d = row - c0;
                bits &= ~((2u << d) - 1u);
            }
            bits &= 0xFFFFu;
        }
        s_mrow[row][g] = (unsigned short)bits;
        if (bits) atomicOr(&s_rnz[row >> 6], 1ull << (row & 63));
    }
    __syncthreads();                                          // B7

    // ---- greedy scan with parallel batch-emit of non-suppressor runs ----
    if (wv == 0) {
        u64 w0 = (C >= 64) ? ~0ull : ((1ull << C) - 1ull);
        int nb1 = C - 64;
        u64 w1 = (nb1 >= 64) ? ~0ull : ((nb1 <= 0) ? 0ull : ((1ull << nb1) - 1ull));
        const u64 rz0 = s_rnz[0];
        const u64 rz1 = s_rnz[1];
        int kept = 0;

        while (kept < top_k && w0 != 0ull) {
            u64 sup = w0 & rz0;
            u64 batch = sup ? (w0 & ((1ull << (unsigned)__builtin_ctzll(sup)) - 1ull)) : w0;
            int nb = __builtin_popcountll(batch);
            int emit = (nb < top_k - kept) ? nb : (top_k - kept);
            if ((batch >> lane) & 1ull) {
                int rank = __builtin_popcountll(batch & ((1ull << lane) - 1ull));
                if (rank < emit) s_keeppos[kept + rank] = (short)lane;
            }
            kept += emit;
            w0 &= ~batch;
            if (kept >= top_k || w0 == 0ull) break;
            int b = __builtin_ctzll(w0);
            if (lane == 0) s_keeppos[kept] = (short)b;
            kept++;
            uint4 rw = *(const uint4*)&s_mrow[b][0];
            u64 r0 = ((u64)rw.y << 32) | rw.x;
            u64 r1 = ((u64)rw.w << 32) | rw.z;
            w0 &= ~(1ull << b);
            w0 &= ~r0;
            w1 &= ~r1;
        }
        while (kept < top_k && w1 != 0ull) {
            u64 sup = w1 & rz1;
            u64 batch = sup ? (w1 & ((1ull << (unsigned)__builtin_ctzll(sup)) - 1ull)) : w1;
            int nb = __builtin_popcountll(batch);
            int emit = (nb < top_k - kept) ? nb : (top_k - kept);
            if ((batch >> lane) & 1ull) {
                int rank = __builtin_popcountll(batch & ((1ull << lane) - 1ull));
                if (rank < emit) s_keeppos[kept + rank] = (short)(64 + lane);
            }
            kept += emit;
            w1 &= ~batch;
            if (kept >= top_k || w1 == 0ull) break;
            int b = __builtin_ctzll(w1);
            if (lane == 0) s_keeppos[kept] = (short)(64 + b);
            kept++;
            uint4 rw = *(const uint4*)&s_mrow[64 + b][0];
            u64 r1 = ((u64)rw.w << 32) | rw.z;
            w1 &= ~(1ull << b);
            w1 &= ~r1;
        }
        if (lane == 0) s_nkept = kept;
    }
    __syncthreads();                                          // B8

    // ---- output: [score, det0, det1, det2, det4, det5, det8, det9] ----
    const int nkept = s_nkept;
    const int total = top_k * 8;
    if (tid < total) {
        int r = tid >> 3;
        int col = tid & 7;
        float v = 0.0f;
        if (r < nkept) {
            int pos = (int)s_keeppos[r];
            u64 kk64 = s_sorted[pos];
            int idx = (int)(unsigned)(kk64 & 0xFFFFFFFFull);
            if (col == 0) {
                // exact score recovery: key = ~(bits(s)|sign) -> bits(s) = ~key & 0x7FFFFFFF
                unsigned k32 = (unsigned)(kk64 >> 32);
                v = __uint_as_float((~k32) & 0x7FFFFFFFu);
            } else {
                int j = (col <= 3) ? (col - 1) : ((col <= 5) ? col : (col + 2));
                float a;
                if (j == 2) a = 0.0f;
                else        a = (j & 1) ? anchors[idx * 2 + 1] : anchors[idx * 2 + 0];
                v = y[idx * 18 + j] * inv128 + a;
            }
        }
        out[tid] = v;
    }
}

extern "C" void kernel_launch(void* const* d_in, const int* in_sizes, int n_in,
                              void* d_out, int out_size, void* d_ws, size_t ws_size,
                              hipStream_t stream) {
    const float* x       = (const float*)d_in[0];   // (1, 8192, 1)
    const float* y       = (const float*)d_in[1];   // (1, 8192, 18)
    const float* anchors = (const float*)d_in[2];   // (8192, 2)
    float* out = (float*)d_out;                     // (top_k, 8) f32

    int top_k = out_size / 8;
    if (top_k > TOPK_CAP) top_k = TOPK_CAP;

    pd_post_kernel<<<1, NT, 0, stream>>>(x, y, anchors, out, top_k);
}

// Round 16
// 16.595 us; speedup vs baseline: 1.0445x; 1.0445x over previous
//
#include <hip/hip_runtime.h>
#include <math.h>

#define N_BOX 8192
#define NT 1024
#define TOPK_CAP 128
#define IOU_THR 0.3f
#define M_TARGET 116u
#define CAP_C 128
#define BINA_SHIFT 22        // 10-bit coarse bin
#define BINB_SHIFT 12        // bits [12,22) refine (1024 bins)
#define SENT 0xFFFFFFFFu

typedef unsigned long long u64;

// scan 1024-bin histogram for cumulative crossing of `target`
__device__ __forceinline__ void wave_scan_1024(const unsigned* hist,
                                               unsigned* outw,
                                               unsigned target, int lane)
{
    uint4 h0 = ((const uint4*)hist)[lane * 4 + 0];
    uint4 h1 = ((const uint4*)hist)[lane * 4 + 1];
    uint4 h2 = ((const uint4*)hist)[lane * 4 + 2];
    uint4 h3 = ((const uint4*)hist)[lane * 4 + 3];
    unsigned b[16] = {h0.x, h0.y, h0.z, h0.w, h1.x, h1.y, h1.z, h1.w,
                      h2.x, h2.y, h2.z, h2.w, h3.x, h3.y, h3.z, h3.w};
    unsigned s = 0;
#pragma unroll
    for (int k = 0; k < 16; k++) s += b[k];
    unsigned incl = s;
    for (int off = 1; off < 64; off <<= 1) {
        unsigned n = __shfl_up(incl, off);
        if (lane >= off) incl += n;
    }
    unsigned excl = incl - s;
    if (excl < target && excl + s >= target) {
        unsigned run = excl;
        bool found = false;
#pragma unroll
        for (int k = 0; k < 16; k++) {
            unsigned nrun = run + b[k];
            if (!found && nrun >= target) {
                outw[0] = (unsigned)(lane * 16 + k);
                outw[1] = nrun;
                outw[2] = run;
                found = true;
            }
            run = nrun;
        }
    }
}

// ------ single fused kernel: keys + select + sort + decode + NMS + output ------
__global__ __launch_bounds__(NT)
void pd_post_kernel(const float* __restrict__ x,
                    const float* __restrict__ y,
                    const float* __restrict__ anchors,
                    float* __restrict__ out,
                    int top_k)
{
#pragma clang fp contract(off)
    __shared__ unsigned s_histA[1024];                 // fallback only
    __shared__ unsigned s_histB[1024];
    __shared__ unsigned s_wred[16];
    __shared__ unsigned s_scan[8];                     // [0..2] B-scan, [3]=G, [4..6] A-scan
    __shared__ u64 s_cand[CAP_C];
    __shared__ u64 s_sorted[CAP_C];
    __shared__ float4 s_sbox[CAP_C];
    __shared__ unsigned short s_mrow[CAP_C][8];
    __shared__ u64 s_rnz[2];
    __shared__ short s_keeppos[TOPK_CAP];
    __shared__ int s_cnt, s_nkept;

    const int tid = threadIdx.x;
    const int lane = tid & 63;
    const int wv = tid >> 6;
    const float inv128 = 0.0078125f;

    // ---- issue x loads first (32 KB coalesced) ----
    const uint4* xp = (const uint4*)x;
    uint4 xa = xp[tid * 2 + 0];
    uint4 xb = xp[tid * 2 + 1];

    // ---- init LDS while loads are in flight (fast path: histB only) ----
    if (tid == 0) s_cnt = 0;
    if (tid < 2) s_rnz[tid] = 0ull;
    if (tid < 8) s_scan[tid] = SENT;
    if (tid < 256) {
        uint4 z = make_uint4(0u, 0u, 0u, 0u);
        ((uint4*)s_histB)[tid] = z;
    }
    if (tid < CAP_C) { s_cand[tid] = ~0ull; s_sorted[tid] = ~0ull; }

    // ---- keys = ~(bits(sigmoid(x))|sign), in registers ----
    unsigned xs[8] = {xa.x, xa.y, xa.z, xa.w, xb.x, xb.y, xb.z, xb.w};
    unsigned myk[8];
    unsigned mymin = 0xFFFFFFFFu;
#pragma unroll
    for (int k = 0; k < 8; k++) {
        float xv = __uint_as_float(xs[k]);
        float s = 1.0f / (1.0f + expf(-xv));
        unsigned kk = ~(__float_as_uint(s) | 0x80000000u);
        myk[k] = kk;
        mymin = (kk < mymin) ? kk : mymin;
    }

    // ---- block min -> first nonempty coarse bin G (no atomics) ----
#pragma unroll
    for (int off = 32; off >= 1; off >>= 1) {
        unsigned o = (unsigned)__shfl_xor((int)mymin, off);
        mymin = (o < mymin) ? o : mymin;
    }
    if (lane == 0) s_wred[wv] = mymin;
    __syncthreads();                                          // B1
    if (wv == 0) {
        unsigned v = (lane < 16) ? s_wred[lane] : 0xFFFFFFFFu;
#pragma unroll
        for (int off = 8; off >= 1; off >>= 1) {
            unsigned o = (unsigned)__shfl_xor((int)v, off);
            v = (o < v) ? o : v;
        }
        if (lane == 0) s_scan[3] = v >> BINA_SHIFT;
    }
    __syncthreads();                                          // B2
    const unsigned G = s_scan[3];

    // ---- fast pass-B: histogram bin-G keys on bits [12,22) ----
#pragma unroll
    for (int k = 0; k < 8; k++)
        if ((myk[k] >> BINA_SHIFT) == G)
            atomicAdd(&s_histB[(myk[k] >> BINB_SHIFT) & 1023u], 1u);
    __syncthreads();                                          // B3
    if (wv == 0) wave_scan_1024(s_histB, &s_scan[0], M_TARGET, lane);
    __syncthreads();                                          // B4

    unsigned B1bin, B2sub;
    int C;
    if (s_scan[0] != SENT) {
        // fast path: bin G contains the M_TARGET-th key
        B1bin = G;
        B2sub = s_scan[0];
        C = (int)s_scan[1];
    } else {
        // ---- fallback (block-uniform; proven two-level path) ----
        if (tid < 256) {
            uint4 z = make_uint4(0u, 0u, 0u, 0u);
            ((uint4*)s_histA)[tid] = z;
        }
        __syncthreads();
#pragma unroll
        for (int k = 0; k < 8; k++)
            atomicAdd(&s_histA[myk[k] >> BINA_SHIFT], 1u);
        __syncthreads();
        if (wv == 0) wave_scan_1024(s_histA, &s_scan[4], M_TARGET, lane);
        __syncthreads();
        B1bin = s_scan[4];
        unsigned n0 = s_scan[6];
        if (tid < 256) {
            uint4 z = make_uint4(0u, 0u, 0u, 0u);
            ((uint4*)s_histB)[tid] = z;
        }
        __syncthreads();
#pragma unroll
        for (int k = 0; k < 8; k++)
            if ((myk[k] >> BINA_SHIFT) == B1bin)
                atomicAdd(&s_histB[(myk[k] >> BINB_SHIFT) & 1023u], 1u);
        __syncthreads();
        if (wv == 0) wave_scan_1024(s_histB, &s_scan[0], M_TARGET - n0, lane);
        __syncthreads();
        B2sub = s_scan[0];
        C = (int)(n0 + s_scan[1]);
    }
    if (C > CAP_C) C = CAP_C;

    // ---- compact selected candidates (u64 key<<32|idx, unique) ----
#pragma unroll
    for (int k = 0; k < 8; k++) {
        unsigned kk = myk[k];
        unsigned b1 = kk >> BINA_SHIFT;
        bool sel = (b1 < B1bin) || (b1 == B1bin && ((kk >> BINB_SHIFT) & 1023u) <= B2sub);
        if (sel) {
            int p = atomicAdd(&s_cnt, 1);
            if (p < CAP_C)
                s_cand[p] = (((u64)kk) << 32) | (unsigned)(tid * 8 + k);
        }
    }
    __syncthreads();                                          // B5

    // ---- rank sort (fixed 128-wide, keys unique, pads ~0ull) ----
    if (tid < CAP_C) {
        u64 me = s_cand[tid];
        int rank = 0;
        const ulonglong2* cp = (const ulonglong2*)s_cand;
#pragma unroll
        for (int j = 0; j < CAP_C / 2; j += 4) {
            ulonglong2 a = cp[j + 0];
            ulonglong2 b = cp[j + 1];
            ulonglong2 d = cp[j + 2];
            ulonglong2 e = cp[j + 3];
            rank += (a.x < me) + (a.y < me) + (b.x < me) + (b.y < me)
                  + (d.x < me) + (d.y < me) + (e.x < me) + (e.y < me);
        }
        if (me != ~0ull) s_sorted[rank] = me;
    }
    __syncthreads();                                          // B6

    // ---- gather y/anchors for candidates only; decode boxes ----
    if (tid < CAP_C) {
        if (tid < C) {
            int idx = (int)(unsigned)(s_sorted[tid] & 0xFFFFFFFFull);
            const float2* yr = (const float2*)(y + idx * 18);
            float2 ya = yr[0];
            float2 yb2 = yr[1];
            float2 an = ((const float2*)anchors)[idx];
            float cx = ya.x * inv128 + an.x;
            float cy = ya.y * inv128 + an.y;
            float w2 = (yb2.x * inv128) * 0.5f;
            float h2 = (yb2.y * inv128) * 0.5f;
            s_sbox[tid] = make_float4(cx - w2, cy - h2, cx + w2, cy + h2);
        } else {
            s_sbox[tid] = make_float4(3e30f, 3e30f, 3e30f, 3e30f);
        }
    }
    __syncthreads();                                          // B7

    // ---- build upper-tri suppression matrix: (row, 16-col group) per thread ----
    {
        int row = tid >> 3;
        int g = tid & 7;
        int c0 = g << 4;
        unsigned bits = 0u;
        if (c0 + 15 > row) {
            float4 A = s_sbox[row];
            float aA = (A.z - A.x) * (A.w - A.y);
#pragma unroll
            for (int k = 0; k < 16; ++k) {
                int kk = (k + row) & 15;                     // stagger reads
                float4 Bx = s_sbox[c0 + kk];
                float ba = (Bx.z - Bx.x) * (Bx.w - Bx.y);
                float iw = fmaxf(fminf(A.z, Bx.z) - fmaxf(A.x, Bx.x), 0.0f);
                float ih = fmaxf(fminf(A.w, Bx.w) - fmaxf(A.y, Bx.y), 0.0f);
                float inter = iw * ih;
                float iou = inter / (aA + ba - inter);
                if (iou > IOU_THR) bits |= (1u << kk);
            }
            if (row >= c0) {
                int d = row - c0;
                bits &= ~((2u << d) - 1u);
            }
            bits &= 0xFFFFu;
        }
        s_mrow[row][g] = (unsigned short)bits;
        if (bits) atomicOr(&s_rnz[row >> 6], 1ull << (row & 63));
    }
    __syncthreads();                                          // B8

    // ---- greedy scan with parallel batch-emit of non-suppressor runs ----
    if (wv == 0) {
        u64 w0 = (C >= 64) ? ~0ull : ((1ull << C) - 1ull);
        int nb1 = C - 64;
        u64 w1 = (nb1 >= 64) ? ~0ull : ((nb1 <= 0) ? 0ull : ((1ull << nb1) - 1ull));
        const u64 rz0 = s_rnz[0];
        const u64 rz1 = s_rnz[1];
        int kept = 0;

        while (kept < top_k && w0 != 0ull) {
            u64 sup = w0 & rz0;
            u64 batch = sup ? (w0 & ((1ull << (unsigned)__builtin_ctzll(sup)) - 1ull)) : w0;
            int nb = __builtin_popcountll(batch);
            int emit = (nb < top_k - kept) ? nb : (top_k - kept);
            if ((batch >> lane) & 1ull) {
                int rank = __builtin_popcountll(batch & ((1ull << lane) - 1ull));
                if (rank < emit) s_keeppos[kept + rank] = (short)lane;
            }
            kept += emit;
            w0 &= ~batch;
            if (kept >= top_k || w0 == 0ull) break;
            int b = __builtin_ctzll(w0);
            if (lane == 0) s_keeppos[kept] = (short)b;
            kept++;
            uint4 rw = *(const uint4*)&s_mrow[b][0];
            u64 r0 = ((u64)rw.y << 32) | rw.x;
            u64 r1 = ((u64)rw.w << 32) | rw.z;
            w0 &= ~(1ull << b);
            w0 &= ~r0;
            w1 &= ~r1;
        }
        while (kept < top_k && w1 != 0ull) {
            u64 sup = w1 & rz1;
            u64 batch = sup ? (w1 & ((1ull << (unsigned)__builtin_ctzll(sup)) - 1ull)) : w1;
            int nb = __builtin_popcountll(batch);
            int emit = (nb < top_k - kept) ? nb : (top_k - kept);
            if ((batch >> lane) & 1ull) {
                int rank = __builtin_popcountll(batch & ((1ull << lane) - 1ull));
                if (rank < emit) s_keeppos[kept + rank] = (short)(64 + lane);
            }
            kept += emit;
            w1 &= ~batch;
            if (kept >= top_k || w1 == 0ull) break;
            int b = __builtin_ctzll(w1);
            if (lane == 0) s_keeppos[kept] = (short)(64 + b);
            kept++;
            uint4 rw = *(const uint4*)&s_mrow[64 + b][0];
            u64 r1 = ((u64)rw.w << 32) | rw.z;
            w1 &= ~(1ull << b);
            w1 &= ~r1;
        }
        if (lane == 0) s_nkept = kept;
    }
    __syncthreads();                                          // B9

    // ---- output: [score, det0, det1, det2, det4, det5, det8, det9] ----
    const int nkept = s_nkept;
    const int total = top_k * 8;
    if (tid < total) {
        int r = tid >> 3;
        int col = tid & 7;
        float v = 0.0f;
        if (r < nkept) {
            int pos = (int)s_keeppos[r];
            u64 kk64 = s_sorted[pos];
            int idx = (int)(unsigned)(kk64 & 0xFFFFFFFFull);
            if (col == 0) {
                // exact score recovery: key = ~(bits(s)|sign) -> bits(s) = ~key & 0x7FFFFFFF
                unsigned k32 = (unsigned)(kk64 >> 32);
                v = __uint_as_float((~k32) & 0x7FFFFFFFu);
            } else {
                int j = (col <= 3) ? (col - 1) : ((col <= 5) ? col : (col + 2));
                float a;
                if (j == 2) a = 0.0f;
                else        a = (j & 1) ? anchors[idx * 2 + 1] : anchors[idx * 2 + 0];
                v = y[idx * 18 + j] * inv128 + a;
            }
        }
        out[tid] = v;
    }
}

extern "C" void kernel_launch(void* const* d_in, const int* in_sizes, int n_in,
                              void* d_out, int out_size, void* d_ws, size_t ws_size,
                              hipStream_t stream) {
    const float* x       = (const float*)d_in[0];   // (1, 8192, 1)
    const float* y       = (const float*)d_in[1];   // (1, 8192, 18)
    const float* anchors = (const float*)d_in[2];   // (8192, 2)
    float* out = (float*)d_out;                     // (top_k, 8) f32

    int top_k = out_size / 8;
    if (top_k > TOPK_CAP) top_k = TOPK_CAP;

    pd_post_kernel<<<1, NT, 0, stream>>>(x, y, anchors, out, top_k);
}